// Round 7
// baseline (159.442 us; speedup 1.0000x reference)
//
#include <hip/hip_runtime.h>
#include <hip/hip_bf16.h>

// Problem: B=2, L=64, F=128. Output (B, L(a), L(t), L(s), 2F) f32 = 512 MiB.
// out[b,a,t,s,0:128]   = mask * (P[b,s]-P[b,a])/(s-a)   [sign cancels]
// out[b,a,t,s,128:256] = mask * (P[b,s]-P[b,t])/(s-t)
// mask = (a!=t)&(a!=s)&(t!=s); P[k] = sum x[0..k-1] (P[64] never used).
// Pure write-BW bound: 512 MiB out, 64 KiB in.
//
// R7: SINGLE fused kernel. Each block recomputes the P columns it needs from
// x (64 KiB, L1-resident) via an in-register cumsum with uniform-branch
// captures -> no prefix dispatch, no serial graph edge. t-group widened to 8
// (1024 blocks, 512 KiB contiguous each). Plain stores (R5: nt hurts).

#define B_ 2
#define L_ 64
#define F_ 128

typedef float f32x4 __attribute__((ext_vector_type(4)));

__global__ __launch_bounds__(256) void writer_kernel(f32x4* __restrict__ out,
                                                     const float* __restrict__ x) {
    const int bid = blockIdx.x;          // (b*64 + a)*8 + tg
    const int tg = bid & 7;
    const int a  = (bid >> 3) & 63;
    const int b  = bid >> 9;
    const int t0 = tg << 3;
    const int tid = threadIdx.x;
    const int f4 = tid & 63;             // float4 index within the 256-float row
    const int sw = tid >> 6;             // wave id 0..3
    const int s0 = sw << 4;              // this wave's first s

    // out index (f32x4 units): (((b*64+a)*64 + t)*64 + s)*64 + f4
    f32x4* o = out + ((size_t)(((b << 6) + a) << 6) + t0) * 4096 + s0 * 64 + f4;

    const bool lower = (f4 < 32);        // lanes 0..31: i=a half; 32..63: i=t half
    const int c = (f4 & 31) << 2;        // float column offset 0..124
    const float* xb = x + (b << 13) + c; // b*64*128 + c

    // In-register cumsum over the 64 rows of x; capture the P rows this
    // thread needs. All branch conditions are wave/block-uniform and all
    // array indices are compile-time constants (full unroll) -> no scratch.
    f32x4 p[16];                          // P[s0 + 0..15]
    f32x4 pt[8];                          // P[t0 + 0..7]
    f32x4 pa  = {0.f, 0.f, 0.f, 0.f};
    f32x4 run = {0.f, 0.f, 0.f, 0.f};
#pragma unroll
    for (int r = 0; r < L_; ++r) {       // invariant: run == P[r]
        if ((r >> 4) == sw) p[r & 15] = run;
        if ((r >> 3) == tg) pt[r & 7] = run;
        if (r == a)         pa        = run;
        run += *reinterpret_cast<const f32x4*>(xb + (r << 7));
    }

    const f32x4 z = {0.f, 0.f, 0.f, 0.f};
    const float fa = (float)a;

#pragma unroll
    for (int tt = 0; tt < 8; ++tt) {
        const int t = t0 + tt;
        const bool plane_zero = (a == t);            // block-uniform
        const f32x4 pi = lower ? pa : pt[tt];        // per-lane select
        const float fi = lower ? fa : (float)t;
        f32x4* ot = o + tt * 4096;

#pragma unroll
        for (int k = 0; k < 16; ++k) {
            const int s = s0 + k;                    // wave-uniform
            f32x4 v;
            if (plane_zero || s == a || s == t) {    // wave-uniform
                v = z;
            } else {                                  // here s != i for all lanes
                const float r = __builtin_amdgcn_rcpf((float)s - fi);
                v = (p[k] - pi) * r;
            }
            ot[k * 64] = v;
        }
    }
}

extern "C" void kernel_launch(void* const* d_in, const int* in_sizes, int n_in,
                              void* d_out, int out_size, void* d_ws, size_t ws_size,
                              hipStream_t stream) {
    const float* x = (const float*)d_in[0];
    f32x4* out = (f32x4*)d_out;

    writer_kernel<<<B_ * L_ * (L_ / 8), 256, 0, stream>>>(out, x);
}

// Round 8
// 102.824 us; speedup vs baseline: 1.5506x; 1.5506x over previous
//
#include <hip/hip_runtime.h>
#include <hip/hip_bf16.h>

// Problem: B=2, L=64, F=128. Output (B, L(a), L(t), L(s), 2F) f32 = 512 MiB.
// out[b,a,t,s,0:128]   = mask * (P[b,s]-P[b,a])/(s-a)   [sign cancels]
// out[b,a,t,s,128:256] = mask * (P[b,s]-P[b,t])/(s-t)
// mask = (a!=t)&(a!=s)&(t!=s).  Pure write-BW bound: 512 MiB out, 64 KiB in.
//
// R8: revert R7 fusion (spill/occupancy regression). R6 two-kernel structure,
// t-group widened 4 -> 8 (1024 blocks, 512 KiB each). p[16] kept in regs
// (shared across 8 t-planes); pt loaded per-plane in-loop (L1-hit, proven
// free in R3/R4) to keep VGPR pressure BELOW R6. Plain stores (R5: nt hurts).

#define B_ 2
#define L_ 64
#define F_ 128

typedef float f32x4 __attribute__((ext_vector_type(4)));

__device__ float g_P[B_ * (L_ + 1) * F_];   // prefix sums, 66.5 KB

__global__ void prefix_kernel(const float* __restrict__ x) {
    const int b = blockIdx.x;       // 0..1
    const int f = threadIdx.x;      // 0..127
    const float* xb = x + b * L_ * F_ + f;
    float* Pb = g_P + b * (L_ + 1) * F_ + f;

    float v[L_];
#pragma unroll
    for (int r = 0; r < L_; ++r) v[r] = xb[r * F_];

    float run = 0.0f;
    Pb[0] = 0.0f;
#pragma unroll
    for (int r = 0; r < L_; ++r) {
        run += v[r];
        Pb[(r + 1) * F_] = run;
    }
}

// One block per (b, a, t-group of 8): 1024 blocks, 512 KiB contiguous each.
// 4 waves; wave w owns s in [16w, 16w+16) for every t in the group.
__global__ __launch_bounds__(256) void writer_kernel(f32x4* __restrict__ out) {
    const int bid = blockIdx.x;          // (b*64 + a)*8 + tg
    const int tg = bid & 7;
    const int a  = (bid >> 3) & 63;
    const int b  = bid >> 9;
    const int t0 = tg << 3;
    const int tid = threadIdx.x;
    const int f4 = tid & 63;             // float4 index within the 256-float row
    const int s0 = (tid >> 6) << 4;      // this wave's first s

    // out index (f32x4 units): (((b*64+a)*64 + t)*64 + s)*64 + f4
    f32x4* o = out + ((size_t)(((b << 6) + a) << 6) + t0) * 4096 + s0 * 64 + f4;

    const f32x4 z = {0.f, 0.f, 0.f, 0.f};
    const bool lower = (f4 < 32);        // lanes 0..31: i=a half; 32..63: i=t half
    const float* base = g_P + ((b * (L_ + 1)) << 7) + ((f4 & 31) << 2);

    // Wave's s-range of P, shared across all 8 t-planes.
    f32x4 p[16];
#pragma unroll
    for (int k = 0; k < 16; ++k)
        p[k] = *reinterpret_cast<const f32x4*>(base + ((s0 + k) << 7));
    const f32x4 pa = *reinterpret_cast<const f32x4*>(base + (a << 7));
    const float fa = (float)a;

#pragma unroll
    for (int tt = 0; tt < 8; ++tt) {
        const int t = t0 + tt;
        const bool plane_zero = (a == t);            // block-uniform
        // per-plane P[t]: in-loop L1-hit load (keeps live regs low)
        const f32x4 ptv = *reinterpret_cast<const f32x4*>(base + (t << 7));
        const f32x4 pi = lower ? pa : ptv;           // per-lane select
        const float fi = lower ? fa : (float)t;
        f32x4* ot = o + tt * 4096;

#pragma unroll
        for (int k = 0; k < 16; ++k) {
            const int s = s0 + k;                    // wave-uniform
            f32x4 v;
            if (plane_zero || s == a || s == t) {    // wave-uniform
                v = z;
            } else {                                  // here s != i for all lanes
                const float r = __builtin_amdgcn_rcpf((float)s - fi);
                v = (p[k] - pi) * r;
            }
            ot[k * 64] = v;
        }
    }
}

extern "C" void kernel_launch(void* const* d_in, const int* in_sizes, int n_in,
                              void* d_out, int out_size, void* d_ws, size_t ws_size,
                              hipStream_t stream) {
    const float* x = (const float*)d_in[0];
    f32x4* out = (f32x4*)d_out;

    prefix_kernel<<<B_, F_, 0, stream>>>(x);
    writer_kernel<<<B_ * L_ * (L_ / 8), 256, 0, stream>>>(out);
}